// Round 1
// baseline (385.963 us; speedup 1.0000x reference)
//
#include <hip/hip_runtime.h>

typedef unsigned int u32;
typedef unsigned short u16;
typedef unsigned long long u64;

typedef __attribute__((ext_vector_type(8))) short s8v;   // 8 bf16 (4 VGPRs)
typedef __attribute__((ext_vector_type(4))) float f4v;   // 4 fp32 acc

#define B_SZ   8192
#define V_SZ   1000
#define KCH    5
#define MAXDEG 32

__device__ __forceinline__ u16 f2bf(float f) {
    u32 u = __float_as_uint(f);
    u32 r = (u + 0x7FFFu + ((u >> 16) & 1u)) >> 16;   // RNE
    return (u16)r;
}
__device__ __forceinline__ float bf2f(u16 h) { return __uint_as_float(((u32)h) << 16); }

// ---------------------------------------------------------------------------
// K0: build packed sparse Lr (off-diag) + diagonal. One wave per row.
// packed entry: (fp32 weight with low 10 mantissa bits cleared) | col (10 bits)
// ---------------------------------------------------------------------------
__global__ __launch_bounds__(256) void k_build(const float* __restrict__ L,
                                               const float* __restrict__ lmax,
                                               u32* __restrict__ packed,
                                               int* __restrict__ cnts,
                                               float* __restrict__ diagw) {
    int wid  = threadIdx.x >> 6;
    int lane = threadIdx.x & 63;
    int row  = blockIdx.x * 4 + wid;
    if (row >= V_SZ) return;
    float s = 2.0f / lmax[0];
    const float* Lrow = L + (u64)row * V_SZ;
    int cnt = 0;
    for (int c0 = 0; c0 < V_SZ; c0 += 64) {
        int c = c0 + lane;
        float val = 0.0f;
        if (c < V_SZ && c != row) val = Lrow[c];
        bool nz = (val != 0.0f);
        u64 m = __ballot(nz);
        int pos = cnt + __popcll(m & ((1ull << lane) - 1ull));
        if (nz && pos < MAXDEG) {
            u32 w = __float_as_uint(val * s);
            packed[row * MAXDEG + pos] = (w & 0xFFFFFC00u) | (u32)c;
        }
        cnt += __popcll(m);
    }
    if (lane == 0) {
        cnts[row]  = cnt < MAXDEG ? cnt : MAXDEG;
        diagw[row] = s * Lrow[row] - 1.0f;
    }
}

// ---------------------------------------------------------------------------
// Kpre: weight conversions to bf16 (+K padding) and folded BN affine params.
// ---------------------------------------------------------------------------
__global__ __launch_bounds__(256) void k_pre(const float* __restrict__ fc1W,
                                             const float* __restrict__ lin1W,
                                             const float* __restrict__ gam,
                                             const float* __restrict__ bet,
                                             const float* __restrict__ mea,
                                             const float* __restrict__ var,
                                             u16* __restrict__ fc1w_b,
                                             u16* __restrict__ lin1w_b,
                                             float* __restrict__ bn_a,
                                             float* __restrict__ bn_c) {
    int t = blockIdx.x * 256 + threadIdx.x;
    if (t < 256 * 640) {
        int r = t / 640, c = t - r * 640;
        fc1w_b[t] = (c < 625) ? f2bf(fc1W[r * 625 + c]) : (u16)0;
    }
    if (t < 256 * 256) lin1w_b[t] = f2bf(lin1W[t]);
    if (t < 4 * 256) {
        float a = gam[t] * rsqrtf(var[t] + 1e-5f);
        bn_a[t] = a;
        bn_c[t] = bet[t] - mea[t] * a;
    }
}

// ---------------------------------------------------------------------------
// K1: fused Chebyshev recursion (fp32, in LDS) + cl1 + ReLU + maxpool8 -> bf16
// One workgroup handles 2 columns (batch rows) end-to-end.
// LDS: xs[5][1000][2] fp32 = 40 KB.
// ---------------------------------------------------------------------------
__global__ __launch_bounds__(256) void k_cheby(const float* __restrict__ x,
                                               const u32* __restrict__ packed,
                                               const int* __restrict__ cnts,
                                               const float* __restrict__ diagw,
                                               const float* __restrict__ cl1W,
                                               const float* __restrict__ cl1b,
                                               u16* __restrict__ pooled) {
    __shared__ float xs[KCH * V_SZ * 2];
    __shared__ float cws[25];
    __shared__ float cbs[5];
    int t  = threadIdx.x;
    int b0 = blockIdx.x * 2;

    if (t < 25) cws[t] = cl1W[t];
    if (t < 5)  cbs[t] = cl1b[t];

    // stage 0: xs[0][v][b] = x[(b0+b)*V + v]  (x is [B,V] row-major)
    for (int e = t; e < V_SZ * 2; e += 256) {
        int v = e >> 1, b = e & 1;
        xs[v * 2 + b] = x[(u64)(b0 + b) * V_SZ + v];
    }
    __syncthreads();

    // stages 1..4: y = Lr @ x_{k-1};  x_1 = y;  x_k = 2y - x_{k-2}
    for (int k = 1; k < KCH; ++k) {
        const float2* xprev = (const float2*)(xs + (k - 1) * V_SZ * 2);
        const float2* xpp   = (const float2*)(xs + (k >= 2 ? (k - 2) : 0) * V_SZ * 2);
        float2*       xcur  = (float2*)(xs + k * V_SZ * 2);
        for (int v = t; v < V_SZ; v += 256) {
            float d  = diagw[v];
            int   cn = cnts[v];
            float2 pv = xprev[v];
            float a0 = d * pv.x, a1 = d * pv.y;
            const u32* pp = packed + v * MAXDEG;
            for (int j = 0; j < cn; ++j) {
                u32 pw = pp[j];
                float w = __uint_as_float(pw & 0xFFFFFC00u);
                float2 nb = xprev[pw & 1023u];
                a0 = fmaf(w, nb.x, a0);
                a1 = fmaf(w, nb.y, a1);
            }
            if (k >= 2) {
                float2 q = xpp[v];
                a0 = 2.0f * a0 - q.x;
                a1 = 2.0f * a1 - q.y;
            }
            xcur[v] = make_float2(a0, a1);
        }
        __syncthreads();
    }

    // combine (cl1 + relu) + maxpool over 8 nodes; write pooled bf16 [B,640]
    if (t < 250) {
        int p = t >> 1, b = t & 1;
        float m[5] = {0.f, 0.f, 0.f, 0.f, 0.f};   // relu => max with 0 is exact
        for (int vg = 0; vg < 8; ++vg) {
            int vv = 8 * p + ((vg + p) & 7);      // rotation kills bank conflicts
            float val[5];
#pragma unroll
            for (int k = 0; k < KCH; ++k) val[k] = xs[(k * V_SZ + vv) * 2 + b];
#pragma unroll
            for (int f = 0; f < 5; ++f) {
                float s = cbs[f];
#pragma unroll
                for (int k = 0; k < 5; ++k) s = fmaf(cws[f * 5 + k], val[k], s);
                m[f] = fmaxf(m[f], s);
            }
        }
        u16* orow = pooled + (u64)(b0 + b) * 640 + p * 5;
#pragma unroll
        for (int f = 0; f < 5; ++f) orow[f] = f2bf(m[f]);
    }
    // zero the K-padding columns 625..639
    if (t < 30) {
        int b = t / 15, c = 625 + (t % 15);
        pooled[(u64)(b0 + b) * 640 + c] = 0;
    }
}

// ---------------------------------------------------------------------------
// K2/K3: bf16 MFMA GEMM, C[m][n] = sum_k A[m][k]*Bw[n][k] (+epilogue)
// BM=128 BN=64 BK=64, 256 thr (4 waves), wave = 32x64 out = 2x4 MFMA tiles.
// MODE 0: + fc1 bias, BN x4 folded affine + relu, JK max  -> bf16
// MODE 1: + lin1 bias, relu                                -> bf16
// ---------------------------------------------------------------------------
template <int MODE>
__global__ __launch_bounds__(256) void k_gemm(const u16* __restrict__ A,
                                              const u16* __restrict__ Bw,
                                              int Kdim,
                                              const float* __restrict__ bias,
                                              const float* __restrict__ bn_a,
                                              const float* __restrict__ bn_c,
                                              u16* __restrict__ Cout) {
    __shared__ u16 As[128][72];   // +8 pad: row stride 36 dw -> 2-way (free)
    __shared__ u16 Bs[64][72];
    int t    = threadIdx.x;
    int lane = t & 63;
    int wid  = t >> 6;
    int m0   = blockIdx.x * 128;
    int n0   = blockIdx.y * 64;

    f4v acc[2][4];
#pragma unroll
    for (int i = 0; i < 2; ++i)
#pragma unroll
        for (int j = 0; j < 4; ++j) acc[i][j] = (f4v){0.f, 0.f, 0.f, 0.f};

    for (int k0 = 0; k0 < Kdim; k0 += 64) {
        int4 ra[4], rb[2];
#pragma unroll
        for (int i = 0; i < 4; ++i) {
            int c = t + i * 256, row = c >> 3, kc = c & 7;
            ra[i] = *(const int4*)(A + (u64)(m0 + row) * Kdim + k0 + kc * 8);
        }
#pragma unroll
        for (int i = 0; i < 2; ++i) {
            int c = t + i * 256, row = c >> 3, kc = c & 7;
            rb[i] = *(const int4*)(Bw + (u64)(n0 + row) * Kdim + k0 + kc * 8);
        }
        __syncthreads();   // prior iter's LDS reads done
#pragma unroll
        for (int i = 0; i < 4; ++i) {
            int c = t + i * 256, row = c >> 3, kc = c & 7;
            *(int4*)(&As[row][kc * 8]) = ra[i];
        }
#pragma unroll
        for (int i = 0; i < 2; ++i) {
            int c = t + i * 256, row = c >> 3, kc = c & 7;
            *(int4*)(&Bs[row][kc * 8]) = rb[i];
        }
        __syncthreads();
#pragma unroll
        for (int ks = 0; ks < 2; ++ks) {
            int kq = ks * 32 + (lane >> 4) * 8;
            s8v af[2], bf[4];
#pragma unroll
            for (int mt = 0; mt < 2; ++mt) {
                int rl = wid * 32 + mt * 16 + (lane & 15);
                af[mt] = *(const s8v*)(&As[rl][kq]);
            }
#pragma unroll
            for (int nt = 0; nt < 4; ++nt) {
                int cl = nt * 16 + (lane & 15);
                bf[nt] = *(const s8v*)(&Bs[cl][kq]);
            }
#pragma unroll
            for (int mt = 0; mt < 2; ++mt)
#pragma unroll
                for (int nt = 0; nt < 4; ++nt)
                    acc[mt][nt] = __builtin_amdgcn_mfma_f32_16x16x32_bf16(
                        af[mt], bf[nt], acc[mt][nt], 0, 0, 0);
        }
    }

    // epilogue: C/D layout col=lane&15, row=(lane>>4)*4+reg  [m89-verified]
#pragma unroll
    for (int nt = 0; nt < 4; ++nt) {
        int col = n0 + nt * 16 + (lane & 15);
        float bv = bias[col];
        float a_[4], c_[4];
        if (MODE == 0) {
#pragma unroll
            for (int i = 0; i < 4; ++i) {
                a_[i] = bn_a[i * 256 + col];
                c_[i] = bn_c[i * 256 + col];
            }
        }
#pragma unroll
        for (int mt = 0; mt < 2; ++mt) {
            int rbase = m0 + wid * 32 + mt * 16 + (lane >> 4) * 4;
#pragma unroll
            for (int r = 0; r < 4; ++r) {
                float v = acc[mt][nt][r] + bv;
                if (MODE == 0) {
                    float h = v, z = 0.0f;
#pragma unroll
                    for (int i = 0; i < 4; ++i) {
                        h = fmaxf(fmaf(a_[i], h, c_[i]), 0.0f);
                        z = fmaxf(z, h);
                    }
                    v = z;
                } else {
                    v = fmaxf(v, 0.0f);
                }
                Cout[(u64)(rbase + r) * 256 + col] = f2bf(v);
            }
        }
    }
}

// ---------------------------------------------------------------------------
// K4: lin2 ([8192,256]@[10,256]^T + b) + log_softmax -> fp32 out
// 64 rows per block, rows staged in LDS (stride 129 dw: conflict-free).
// ---------------------------------------------------------------------------
__global__ __launch_bounds__(256) void k_lin2(const u16* __restrict__ z2,
                                              const float* __restrict__ W2,
                                              const float* __restrict__ b2,
                                              float* __restrict__ out) {
    __shared__ u32   zrow[64 * 129];
    __shared__ float w2s[10 * 256];
    __shared__ float b2s[10];
    __shared__ float lg[64 * 10];
    int t  = threadIdx.x;
    int r0 = blockIdx.x * 64;
    const u32* zg = (const u32*)z2;
    for (int c = t; c < 64 * 128; c += 256) {
        int row = c >> 7, kc = c & 127;
        zrow[row * 129 + kc] = zg[(u64)(r0 + row) * 128 + kc];
    }
    for (int c = t; c < 2560; c += 256) w2s[c] = W2[c];
    if (t < 10) b2s[t] = b2[t];
    __syncthreads();

    int row = t & 63, og = t >> 6;         // outputs o = og + 4j
    int no = (og < 2) ? 3 : 2;
    float acc[3];
#pragma unroll
    for (int j = 0; j < 3; ++j) acc[j] = (og + 4 * j < 10) ? b2s[og + 4 * j] : 0.0f;
    for (int k2 = 0; k2 < 128; ++k2) {
        u32 pz = zrow[row * 129 + k2];
        float z0 = bf2f((u16)(pz & 0xFFFFu));
        float z1 = bf2f((u16)(pz >> 16));
        for (int j = 0; j < no; ++j) {
            int o = og + 4 * j;
            acc[j] = fmaf(z0, w2s[o * 256 + k2 * 2], acc[j]);
            acc[j] = fmaf(z1, w2s[o * 256 + k2 * 2 + 1], acc[j]);
        }
    }
    for (int j = 0; j < no; ++j) lg[row * 10 + og + 4 * j] = acc[j];
    __syncthreads();

    if (t < 64) {
        float l[10], mx = -1e30f;
#pragma unroll
        for (int o = 0; o < 10; ++o) { l[o] = lg[t * 10 + o]; mx = fmaxf(mx, l[o]); }
        float s = 0.0f;
#pragma unroll
        for (int o = 0; o < 10; ++o) s += expf(l[o] - mx);
        float ls = logf(s);
        float* orow = out + (u64)(r0 + t) * 10;
#pragma unroll
        for (int o = 0; o < 10; ++o) orow[o] = l[o] - mx - ls;
    }
}

// ---------------------------------------------------------------------------
extern "C" void kernel_launch(void* const* d_in, const int* in_sizes, int n_in,
                              void* d_out, int out_size, void* d_ws, size_t ws_size,
                              hipStream_t stream) {
    const float* x    = (const float*)d_in[0];
    const float* L    = (const float*)d_in[1];
    const float* lmax = (const float*)d_in[2];
    const float* cl1W = (const float*)d_in[3];
    const float* cl1b = (const float*)d_in[4];
    const float* fc1W = (const float*)d_in[5];
    const float* fc1b = (const float*)d_in[6];
    const float* gam  = (const float*)d_in[7];
    const float* bet  = (const float*)d_in[8];
    const float* mea  = (const float*)d_in[9];
    const float* var  = (const float*)d_in[10];
    const float* l1W  = (const float*)d_in[11];
    const float* l1b  = (const float*)d_in[12];
    const float* l2W  = (const float*)d_in[13];
    const float* l2b  = (const float*)d_in[14];

    char* ws = (char*)d_ws;
    u32*   packed  = (u32*)(ws + 0);          // 128000 -> 131072
    int*   cnts    = (int*)(ws + 131072);     // 4096
    float* diagw   = (float*)(ws + 135168);   // 4096
    float* bn_a    = (float*)(ws + 139264);   // 4096
    float* bn_c    = (float*)(ws + 143360);   // 4096
    u16*   fc1w_b  = (u16*)(ws + 147456);     // 327680
    u16*   lin1w_b = (u16*)(ws + 475136);     // 131072
    u16*   pooled  = (u16*)(ws + 606208);     // 10485760
    u16*   zbuf    = (u16*)(ws + 11091968);   // 4194304
    u16*   z2buf   = (u16*)(ws + 15286272);   // 4194304  (total ~18.6 MB)
    float* outp    = (float*)d_out;

    k_build<<<dim3(250), dim3(256), 0, stream>>>(L, lmax, packed, cnts, diagw);
    k_pre<<<dim3(640), dim3(256), 0, stream>>>(fc1W, l1W, gam, bet, mea, var,
                                               fc1w_b, lin1w_b, bn_a, bn_c);
    k_cheby<<<dim3(4096), dim3(256), 0, stream>>>(x, packed, cnts, diagw,
                                                  cl1W, cl1b, pooled);
    k_gemm<0><<<dim3(64, 4), dim3(256), 0, stream>>>(pooled, fc1w_b, 640, fc1b,
                                                     bn_a, bn_c, zbuf);
    k_gemm<1><<<dim3(64, 4), dim3(256), 0, stream>>>(zbuf, lin1w_b, 256, l1b,
                                                     bn_a, bn_c, z2buf);
    k_lin2<<<dim3(128), dim3(256), 0, stream>>>(z2buf, l2W, l2b, outp);
}

// Round 2
// 353.976 us; speedup vs baseline: 1.0904x; 1.0904x over previous
//
#include <hip/hip_runtime.h>

typedef unsigned int u32;
typedef unsigned short u16;
typedef unsigned long long u64;

typedef __attribute__((ext_vector_type(8))) short s8v;   // 8 bf16 (4 VGPRs)
typedef __attribute__((ext_vector_type(4))) float f4v;   // 4 fp32 acc

#define B_SZ   8192
#define V_SZ   1000
#define KCH    5
#define MAXDEG 32

__device__ __forceinline__ u16 f2bf(float f) {
    u32 u = __float_as_uint(f);
    u32 r = (u + 0x7FFFu + ((u >> 16) & 1u)) >> 16;   // RNE
    return (u16)r;
}
__device__ __forceinline__ float bf2f(u16 h) { return __uint_as_float(((u32)h) << 16); }

// ---------------------------------------------------------------------------
// K0: build packed sparse Lr (off-diag) + diagonal. One wave per row.
// packed entry: (fp32 weight with low 10 mantissa bits cleared) | col (10 bits)
// Tail of each row (cnt..31) is zeroed: weight=0, col=0 -> harmless in gather.
// ---------------------------------------------------------------------------
__global__ __launch_bounds__(256) void k_build(const float* __restrict__ L,
                                               const float* __restrict__ lmax,
                                               u32* __restrict__ packed,
                                               int* __restrict__ cnts,
                                               float* __restrict__ diagw) {
    int wid  = threadIdx.x >> 6;
    int lane = threadIdx.x & 63;
    int row  = blockIdx.x * 4 + wid;
    if (row >= V_SZ) return;
    float s = 2.0f / lmax[0];
    const float* Lrow = L + (u64)row * V_SZ;
    int cnt = 0;
    for (int c0 = 0; c0 < V_SZ; c0 += 64) {
        int c = c0 + lane;
        float val = 0.0f;
        if (c < V_SZ && c != row) val = Lrow[c];
        bool nz = (val != 0.0f);
        u64 m = __ballot(nz);
        int pos = cnt + __popcll(m & ((1ull << lane) - 1ull));
        if (nz && pos < MAXDEG) {
            u32 w = __float_as_uint(val * s);
            packed[row * MAXDEG + pos] = (w & 0xFFFFFC00u) | (u32)c;
        }
        cnt += __popcll(m);
    }
    int cc = cnt < MAXDEG ? cnt : MAXDEG;
    // zero-pad the tail (disjoint addresses from the fills above)
    for (int e = cc + lane; e < MAXDEG; e += 64) packed[row * MAXDEG + e] = 0;
    if (lane == 0) {
        cnts[row]  = cc;
        diagw[row] = s * Lrow[row] - 1.0f;
    }
}

// ---------------------------------------------------------------------------
// Kpre: weight conversions to bf16 (+K padding) and folded BN affine params.
// ---------------------------------------------------------------------------
__global__ __launch_bounds__(256) void k_pre(const float* __restrict__ fc1W,
                                             const float* __restrict__ lin1W,
                                             const float* __restrict__ gam,
                                             const float* __restrict__ bet,
                                             const float* __restrict__ mea,
                                             const float* __restrict__ var,
                                             u16* __restrict__ fc1w_b,
                                             u16* __restrict__ lin1w_b,
                                             float* __restrict__ bn_a,
                                             float* __restrict__ bn_c) {
    int t = blockIdx.x * 256 + threadIdx.x;
    if (t < 256 * 640) {
        int r = t / 640, c = t - r * 640;
        fc1w_b[t] = (c < 625) ? f2bf(fc1W[r * 625 + c]) : (u16)0;
    }
    if (t < 256 * 256) lin1w_b[t] = f2bf(lin1W[t]);
    if (t < 4 * 256) {
        float a = gam[t] * rsqrtf(var[t] + 1e-5f);
        bn_a[t] = a;
        bn_c[t] = bet[t] - mea[t] * a;
    }
}

// ---------------------------------------------------------------------------
// K1: fused Chebyshev recursion + cl1 + ReLU + maxpool8 -> bf16
// One workgroup owns 2 batch columns. 3 rotating LDS stage buffers (24 KB).
// cl1 features accumulated in REGISTERS (cl1 is linear in the basis);
// pooling via 8-lane shuffle max. Sparse row read as int4 (4 entries/step,
// zero-padded) -> 4 independent LDS gathers pipeline back-to-back.
// ---------------------------------------------------------------------------
__global__ __launch_bounds__(256, 4) void k_cheby(const float* __restrict__ x,
                                                  const u32* __restrict__ packed,
                                                  const int* __restrict__ cnts,
                                                  const float* __restrict__ diagw,
                                                  const float* __restrict__ cl1W,
                                                  const float* __restrict__ cl1b,
                                                  u16* __restrict__ pooled) {
    __shared__ float buf[3][V_SZ * 2];   // [stage%3][v*2 + b]  = 24 KB
    __shared__ float cws[25];
    __shared__ float cbs[5];
    int t  = threadIdx.x;
    int b0 = blockIdx.x * 2;

    if (t < 25) cws[t] = cl1W[t];
    if (t < 5)  cbs[t] = cl1b[t];

    // ---- per-thread row metadata + stage 0 staging ----
    bool  valid[4];
    float dwr[4];
    int   nqr[4];
    float x0r[4][2];
#pragma unroll
    for (int i = 0; i < 4; ++i) {
        int v = t + 256 * i;
        valid[i] = (v < V_SZ);
        if (valid[i]) {
            float a = x[(u64)b0 * V_SZ + v];
            float b = x[(u64)(b0 + 1) * V_SZ + v];
            x0r[i][0] = a; x0r[i][1] = b;
            buf[0][v * 2]     = a;
            buf[0][v * 2 + 1] = b;
            dwr[i] = diagw[v];
            nqr[i] = (cnts[v] + 3) >> 2;
        } else {
            x0r[i][0] = 0.f; x0r[i][1] = 0.f;
            dwr[i] = 0.f; nqr[i] = 0;
        }
    }
    __syncthreads();   // publishes buf[0], cws, cbs

    // ---- feat init with k=0 term ----
    float feat[4][5][2];
#pragma unroll
    for (int i = 0; i < 4; ++i)
#pragma unroll
        for (int f = 0; f < 5; ++f) {
            float w = cws[f * 5 + 0];
            feat[i][f][0] = w * x0r[i][0];
            feat[i][f][1] = w * x0r[i][1];
        }

    // ---- stages 1..4 ----
    for (int k = 1; k < KCH; ++k) {
        const float2* prev  = (const float2*)buf[(k - 1) % 3];
        const float2* pprev = (const float2*)buf[(k + 1) % 3];   // == (k-2)%3
        float2*       cur   = (float2*)buf[k % 3];
#pragma unroll
        for (int i = 0; i < 4; ++i) {
            if (!valid[i]) continue;
            int v = t + 256 * i;
            float2 pv = prev[v];
            float a0 = dwr[i] * pv.x, a1 = dwr[i] * pv.y;
            const int4* pp = (const int4*)(packed + v * MAXDEG);
            int nq = nqr[i];
            for (int q = 0; q < nq; ++q) {
                int4 pw = pp[q];
                float2 n0 = prev[(u32)pw.x & 1023u];
                float2 n1 = prev[(u32)pw.y & 1023u];
                float2 n2 = prev[(u32)pw.z & 1023u];
                float2 n3 = prev[(u32)pw.w & 1023u];
                float w0 = __uint_as_float((u32)pw.x & 0xFFFFFC00u);
                float w1 = __uint_as_float((u32)pw.y & 0xFFFFFC00u);
                float w2 = __uint_as_float((u32)pw.z & 0xFFFFFC00u);
                float w3 = __uint_as_float((u32)pw.w & 0xFFFFFC00u);
                a0 = fmaf(w0, n0.x, a0); a1 = fmaf(w0, n0.y, a1);
                a0 = fmaf(w1, n1.x, a0); a1 = fmaf(w1, n1.y, a1);
                a0 = fmaf(w2, n2.x, a0); a1 = fmaf(w2, n2.y, a1);
                a0 = fmaf(w3, n3.x, a0); a1 = fmaf(w3, n3.y, a1);
            }
            if (k >= 2) {
                float2 qq = pprev[v];
                a0 = 2.0f * a0 - qq.x;
                a1 = 2.0f * a1 - qq.y;
            }
            cur[v] = make_float2(a0, a1);
#pragma unroll
            for (int f = 0; f < 5; ++f) {
                float w = cws[f * 5 + k];
                feat[i][f][0] = fmaf(w, a0, feat[i][f][0]);
                feat[i][f][1] = fmaf(w, a1, feat[i][f][1]);
            }
        }
        __syncthreads();
    }

    // ---- bias + ReLU + maxpool8 via 8-lane shuffle, write pooled bf16 ----
    // group of 8 consecutive threads == 8 consecutive v (validity uniform per group)
#pragma unroll
    for (int i = 0; i < 4; ++i) {
#pragma unroll
        for (int f = 0; f < 5; ++f)
#pragma unroll
            for (int b = 0; b < 2; ++b) {
                float s = valid[i] ? fmaxf(feat[i][f][b] + cbs[f], 0.0f) : 0.0f;
                s = fmaxf(s, __shfl_xor(s, 1));
                s = fmaxf(s, __shfl_xor(s, 2));
                s = fmaxf(s, __shfl_xor(s, 4));
                if ((t & 7) == 0 && valid[i]) {
                    int p = (t >> 3) + 32 * i;
                    pooled[(u64)(b0 + b) * 640 + p * 5 + f] = f2bf(s);
                }
            }
    }
    // zero the K-padding columns 625..639
    if (t < 30) {
        int b = t / 15, c = 625 + (t % 15);
        pooled[(u64)(b0 + b) * 640 + c] = 0;
    }
}

// ---------------------------------------------------------------------------
// K2/K3: bf16 MFMA GEMM, C[m][n] = sum_k A[m][k]*Bw[n][k] (+epilogue)
// BM=128 BN=64 BK=64, 256 thr (4 waves), wave = 32x64 out = 2x4 MFMA tiles.
// MODE 0: + fc1 bias, BN x4 folded affine + relu, JK max  -> bf16
// MODE 1: + lin1 bias, relu                                -> bf16
// ---------------------------------------------------------------------------
template <int MODE>
__global__ __launch_bounds__(256) void k_gemm(const u16* __restrict__ A,
                                              const u16* __restrict__ Bw,
                                              int Kdim,
                                              const float* __restrict__ bias,
                                              const float* __restrict__ bn_a,
                                              const float* __restrict__ bn_c,
                                              u16* __restrict__ Cout) {
    __shared__ u16 As[128][72];   // +8 pad: row stride 36 dw -> 2-way (free)
    __shared__ u16 Bs[64][72];
    int t    = threadIdx.x;
    int lane = t & 63;
    int wid  = t >> 6;
    int m0   = blockIdx.x * 128;
    int n0   = blockIdx.y * 64;

    f4v acc[2][4];
#pragma unroll
    for (int i = 0; i < 2; ++i)
#pragma unroll
        for (int j = 0; j < 4; ++j) acc[i][j] = (f4v){0.f, 0.f, 0.f, 0.f};

    for (int k0 = 0; k0 < Kdim; k0 += 64) {
        int4 ra[4], rb[2];
#pragma unroll
        for (int i = 0; i < 4; ++i) {
            int c = t + i * 256, row = c >> 3, kc = c & 7;
            ra[i] = *(const int4*)(A + (u64)(m0 + row) * Kdim + k0 + kc * 8);
        }
#pragma unroll
        for (int i = 0; i < 2; ++i) {
            int c = t + i * 256, row = c >> 3, kc = c & 7;
            rb[i] = *(const int4*)(Bw + (u64)(n0 + row) * Kdim + k0 + kc * 8);
        }
        __syncthreads();   // prior iter's LDS reads done
#pragma unroll
        for (int i = 0; i < 4; ++i) {
            int c = t + i * 256, row = c >> 3, kc = c & 7;
            *(int4*)(&As[row][kc * 8]) = ra[i];
        }
#pragma unroll
        for (int i = 0; i < 2; ++i) {
            int c = t + i * 256, row = c >> 3, kc = c & 7;
            *(int4*)(&Bs[row][kc * 8]) = rb[i];
        }
        __syncthreads();
#pragma unroll
        for (int ks = 0; ks < 2; ++ks) {
            int kq = ks * 32 + (lane >> 4) * 8;
            s8v af[2], bf[4];
#pragma unroll
            for (int mt = 0; mt < 2; ++mt) {
                int rl = wid * 32 + mt * 16 + (lane & 15);
                af[mt] = *(const s8v*)(&As[rl][kq]);
            }
#pragma unroll
            for (int nt = 0; nt < 4; ++nt) {
                int cl = nt * 16 + (lane & 15);
                bf[nt] = *(const s8v*)(&Bs[cl][kq]);
            }
#pragma unroll
            for (int mt = 0; mt < 2; ++mt)
#pragma unroll
                for (int nt = 0; nt < 4; ++nt)
                    acc[mt][nt] = __builtin_amdgcn_mfma_f32_16x16x32_bf16(
                        af[mt], bf[nt], acc[mt][nt], 0, 0, 0);
        }
    }

    // epilogue: C/D layout col=lane&15, row=(lane>>4)*4+reg  [m89-verified]
#pragma unroll
    for (int nt = 0; nt < 4; ++nt) {
        int col = n0 + nt * 16 + (lane & 15);
        float bv = bias[col];
        float a_[4], c_[4];
        if (MODE == 0) {
#pragma unroll
            for (int i = 0; i < 4; ++i) {
                a_[i] = bn_a[i * 256 + col];
                c_[i] = bn_c[i * 256 + col];
            }
        }
#pragma unroll
        for (int mt = 0; mt < 2; ++mt) {
            int rbase = m0 + wid * 32 + mt * 16 + (lane >> 4) * 4;
#pragma unroll
            for (int r = 0; r < 4; ++r) {
                float v = acc[mt][nt][r] + bv;
                if (MODE == 0) {
                    float h = v, z = 0.0f;
#pragma unroll
                    for (int i = 0; i < 4; ++i) {
                        h = fmaxf(fmaf(a_[i], h, c_[i]), 0.0f);
                        z = fmaxf(z, h);
                    }
                    v = z;
                } else {
                    v = fmaxf(v, 0.0f);
                }
                Cout[(u64)(rbase + r) * 256 + col] = f2bf(v);
            }
        }
    }
}

// ---------------------------------------------------------------------------
// K4: lin2 ([8192,256]@[10,256]^T + b) + log_softmax -> fp32 out
// 64 rows per block, rows staged in LDS (stride 129 dw: conflict-free).
// ---------------------------------------------------------------------------
__global__ __launch_bounds__(256) void k_lin2(const u16* __restrict__ z2,
                                              const float* __restrict__ W2,
                                              const float* __restrict__ b2,
                                              float* __restrict__ out) {
    __shared__ u32   zrow[64 * 129];
    __shared__ float w2s[10 * 256];
    __shared__ float b2s[10];
    __shared__ float lg[64 * 10];
    int t  = threadIdx.x;
    int r0 = blockIdx.x * 64;
    const u32* zg = (const u32*)z2;
    for (int c = t; c < 64 * 128; c += 256) {
        int row = c >> 7, kc = c & 127;
        zrow[row * 129 + kc] = zg[(u64)(r0 + row) * 128 + kc];
    }
    for (int c = t; c < 2560; c += 256) w2s[c] = W2[c];
    if (t < 10) b2s[t] = b2[t];
    __syncthreads();

    int row = t & 63, og = t >> 6;         // outputs o = og + 4j
    int no = (og < 2) ? 3 : 2;
    float acc[3];
#pragma unroll
    for (int j = 0; j < 3; ++j) acc[j] = (og + 4 * j < 10) ? b2s[og + 4 * j] : 0.0f;
    for (int k2 = 0; k2 < 128; ++k2) {
        u32 pz = zrow[row * 129 + k2];
        float z0 = bf2f((u16)(pz & 0xFFFFu));
        float z1 = bf2f((u16)(pz >> 16));
        for (int j = 0; j < no; ++j) {
            int o = og + 4 * j;
            acc[j] = fmaf(z0, w2s[o * 256 + k2 * 2], acc[j]);
            acc[j] = fmaf(z1, w2s[o * 256 + k2 * 2 + 1], acc[j]);
        }
    }
    for (int j = 0; j < no; ++j) lg[row * 10 + og + 4 * j] = acc[j];
    __syncthreads();

    if (t < 64) {
        float l[10], mx = -1e30f;
#pragma unroll
        for (int o = 0; o < 10; ++o) { l[o] = lg[t * 10 + o]; mx = fmaxf(mx, l[o]); }
        float s = 0.0f;
#pragma unroll
        for (int o = 0; o < 10; ++o) s += expf(l[o] - mx);
        float ls = logf(s);
        float* orow = out + (u64)(r0 + t) * 10;
#pragma unroll
        for (int o = 0; o < 10; ++o) orow[o] = l[o] - mx - ls;
    }
}

// ---------------------------------------------------------------------------
extern "C" void kernel_launch(void* const* d_in, const int* in_sizes, int n_in,
                              void* d_out, int out_size, void* d_ws, size_t ws_size,
                              hipStream_t stream) {
    const float* x    = (const float*)d_in[0];
    const float* L    = (const float*)d_in[1];
    const float* lmax = (const float*)d_in[2];
    const float* cl1W = (const float*)d_in[3];
    const float* cl1b = (const float*)d_in[4];
    const float* fc1W = (const float*)d_in[5];
    const float* fc1b = (const float*)d_in[6];
    const float* gam  = (const float*)d_in[7];
    const float* bet  = (const float*)d_in[8];
    const float* mea  = (const float*)d_in[9];
    const float* var  = (const float*)d_in[10];
    const float* l1W  = (const float*)d_in[11];
    const float* l1b  = (const float*)d_in[12];
    const float* l2W  = (const float*)d_in[13];
    const float* l2b  = (const float*)d_in[14];

    char* ws = (char*)d_ws;
    u32*   packed  = (u32*)(ws + 0);          // 128000 -> 131072
    int*   cnts    = (int*)(ws + 131072);     // 4096
    float* diagw   = (float*)(ws + 135168);   // 4096
    float* bn_a    = (float*)(ws + 139264);   // 4096
    float* bn_c    = (float*)(ws + 143360);   // 4096
    u16*   fc1w_b  = (u16*)(ws + 147456);     // 327680
    u16*   lin1w_b = (u16*)(ws + 475136);     // 131072
    u16*   pooled  = (u16*)(ws + 606208);     // 10485760
    u16*   zbuf    = (u16*)(ws + 11091968);   // 4194304
    u16*   z2buf   = (u16*)(ws + 15286272);   // 4194304  (total ~18.6 MB)
    float* outp    = (float*)d_out;

    k_build<<<dim3(250), dim3(256), 0, stream>>>(L, lmax, packed, cnts, diagw);
    k_pre<<<dim3(640), dim3(256), 0, stream>>>(fc1W, l1W, gam, bet, mea, var,
                                               fc1w_b, lin1w_b, bn_a, bn_c);
    k_cheby<<<dim3(4096), dim3(256), 0, stream>>>(x, packed, cnts, diagw,
                                                  cl1W, cl1b, pooled);
    k_gemm<0><<<dim3(64, 4), dim3(256), 0, stream>>>(pooled, fc1w_b, 640, fc1b,
                                                     bn_a, bn_c, zbuf);
    k_gemm<1><<<dim3(64, 4), dim3(256), 0, stream>>>(zbuf, lin1w_b, 256, l1b,
                                                     bn_a, bn_c, z2buf);
    k_lin2<<<dim3(128), dim3(256), 0, stream>>>(z2buf, l2W, l2b, outp);
}